// Round 6
// baseline (74.704 us; speedup 1.0000x reference)
//
#include <hip/hip_runtime.h>
#include <math.h>

#define NN 8192
#define EPSF 1e-6f
#define R 16                // rows per block
#define GX (NN / R)         // 512 blocks -> 2 blocks/CU, 8 waves/CU
#define TB 256

typedef float v2f __attribute__((ext_vector_type(2)));

// ws layout: part[GX] float4 {nr, dr, ns, nds} per-block partials (8 KB).
// Every slot is written every call -> no zero-init needed despite poison.
// Semantics identical to the proven round-0/5 kernels:
//   sr[i] = sum_{T[j] >  T[i]} exp(Pr[j])                  (strict >)
//   ss[i] = sum_{T[j] <= T[i]} es[j] - es[i]               (es = E?exp(Ps):0,
//           diagonal subtracted with the bitwise-identical expression)
// Inner loop packs each pair's two selections {g?er:0, g?0:es} into one
// <2 x float> so the two accumulator adds fuse into one v_pk_add_f32
// (5 -> 4 VALU per pair). Each sum still accumulates only its own
// non-negative terms -> exact-zero gates (sr>0, ss>0) preserved.

__global__ __launch_bounds__(TB) void ds_main(
    const float* __restrict__ Pr, const float* __restrict__ Ps,
    const float* __restrict__ T,  const int* __restrict__ E,
    float4* __restrict__ part) {
  const int tid  = threadIdx.x;
  const int row0 = blockIdx.x * R;

  float Ti[R];
#pragma unroll
  for (int r = 0; r < R; ++r) Ti[r] = T[row0 + r];   // block-uniform -> s_load

  v2f acc[R];                       // {sr, ss} packed per row
#pragma unroll
  for (int r = 0; r < R; ++r) acc[r] = (v2f){0.0f, 0.0f};

  // software-pipelined stream: prefetch chunk k+1 while computing chunk k.
  const int j0 = tid * 4;
  float4 t4  = *(const float4*)(T  + j0);
  float4 pr4 = *(const float4*)(Pr + j0);
  float4 ps4 = *(const float4*)(Ps + j0);
  int4   e4  = *(const int4*)(E  + j0);

  for (int k = 0; k < NN; k += 1024) {
    float4 t4n, pr4n, ps4n; int4 e4n;
    const bool more = (k + 1024) < NN;
    if (more) {
      const int jn = k + 1024 + tid * 4;
      t4n  = *(const float4*)(T  + jn);
      pr4n = *(const float4*)(Pr + jn);
      ps4n = *(const float4*)(Ps + jn);
      e4n  = *(const int4*)(E  + jn);
    }

    const float er0 = __expf(pr4.x), er1 = __expf(pr4.y),
                er2 = __expf(pr4.z), er3 = __expf(pr4.w);
    const float es0 = e4.x ? __expf(ps4.x) : 0.0f;
    const float es1 = e4.y ? __expf(ps4.y) : 0.0f;
    const float es2 = e4.z ? __expf(ps4.z) : 0.0f;
    const float es3 = e4.w ? __expf(ps4.w) : 0.0f;

#pragma unroll
    for (int r = 0; r < R; ++r) {
      const float tr = Ti[r];
      const bool g0 = t4.x > tr, g1 = t4.y > tr,
                 g2 = t4.z > tr, g3 = t4.w > tr;
      v2f t0, t1, t2, t3;
      t0.x = g0 ? er0 : 0.0f;  t0.y = g0 ? 0.0f : es0;
      t1.x = g1 ? er1 : 0.0f;  t1.y = g1 ? 0.0f : es1;
      t2.x = g2 ? er2 : 0.0f;  t2.y = g2 ? 0.0f : es2;
      t3.x = g3 ? er3 : 0.0f;  t3.y = g3 ? 0.0f : es3;
      // tree-combine: short dependency chain on acc[r] (1 add per chunk)
      acc[r] += (t0 + t1) + (t2 + t3);
    }

    if (more) { t4 = t4n; pr4 = pr4n; ps4 = ps4n; e4 = e4n; }
  }

  // wave shuffle reduction, then cross-wave via LDS
  float srf[R], ssf[R];
#pragma unroll
  for (int r = 0; r < R; ++r) {
    srf[r] = acc[r].x;
    ssf[r] = acc[r].y;
    for (int off = 32; off > 0; off >>= 1) {
      srf[r] += __shfl_down(srf[r], off);
      ssf[r] += __shfl_down(ssf[r], off);
    }
  }
  __shared__ float sh[4][2 * R];
  const int wid = tid >> 6, lane = tid & 63;
  if (lane == 0) {
#pragma unroll
    for (int r = 0; r < R; ++r) { sh[wid][r] = srf[r]; sh[wid][R + r] = ssf[r]; }
  }
  __syncthreads();
  __shared__ float fin[2 * R];
  if (tid < 2 * R)
    fin[tid] = sh[0][tid] + sh[1][tid] + sh[2][tid] + sh[3][tid];
  __syncthreads();

  // per-row loss contributions (lanes 0..R-1 of wave 0), reduce to 4 scalars
  float nr = 0.0f, dr = 0.0f, ns = 0.0f, nds = 0.0f;
  if (tid < R) {
    const int   row = row0 + tid;
    const int   e   = E[row];
    const float prv = Pr[row], psv = Ps[row];
    const float es_diag = e ? __expf(psv) : 0.0f;  // identical expr -> exact
    const float srv = fin[tid];
    const float ssv = fin[R + tid] - es_diag;      // complement incl. diagonal
    const float wr  = (e != 0 && srv > 0.0f) ? 1.0f : 0.0f;
    const float wsv = (ssv > 0.0f) ? 1.0f : 0.0f;
    nr  = wr  * (prv - logf(srv + EPSF));
    dr  = wr;
    ns  = wsv * (psv - logf(ssv + EPSF));
    nds = wsv;
  }
  if (tid < 64) {   // wave 0: binary-tree reduce lanes 0..R-1
#pragma unroll
    for (int off = R / 2; off > 0; off >>= 1) {
      nr  += __shfl_down(nr,  off);
      dr  += __shfl_down(dr,  off);
      ns  += __shfl_down(ns,  off);
      nds += __shfl_down(nds, off);
    }
    if (tid == 0) part[blockIdx.x] = make_float4(nr, dr, ns, nds);
  }
}

__global__ __launch_bounds__(256) void ds_finalize(
    const float4* __restrict__ part, float* __restrict__ out) {
  float nr = 0.0f, dr = 0.0f, ns = 0.0f, nds = 0.0f;
  for (int i = threadIdx.x; i < GX; i += 256) {
    float4 p = part[i];
    nr += p.x; dr += p.y; ns += p.z; nds += p.w;
  }
  for (int off = 32; off > 0; off >>= 1) {
    nr  += __shfl_down(nr,  off);
    dr  += __shfl_down(dr,  off);
    ns  += __shfl_down(ns,  off);
    nds += __shfl_down(nds, off);
  }
  __shared__ float sh[4][4];
  const int wid = threadIdx.x >> 6, lane = threadIdx.x & 63;
  if (lane == 0) {
    sh[0][wid] = nr; sh[1][wid] = dr; sh[2][wid] = ns; sh[3][wid] = nds;
  }
  __syncthreads();
  if (threadIdx.x == 0) {
    float NR = sh[0][0] + sh[0][1] + sh[0][2] + sh[0][3];
    float DR = sh[1][0] + sh[1][1] + sh[1][2] + sh[1][3];
    float NS = sh[2][0] + sh[2][1] + sh[2][2] + sh[2][3];
    float DS = sh[3][0] + sh[3][1] + sh[3][2] + sh[3][3];
    out[0] = -NR / DR;
    out[1] = -NS / DS;
  }
}

extern "C" void kernel_launch(void* const* d_in, const int* in_sizes, int n_in,
                              void* d_out, int out_size, void* d_ws, size_t ws_size,
                              hipStream_t stream) {
  const float* Pr = (const float*)d_in[0];
  const float* Ps = (const float*)d_in[1];
  const float* T  = (const float*)d_in[2];
  const int*   E  = (const int*)d_in[3];
  float* out = (float*)d_out;

  float4* part = (float4*)d_ws;   // GX float4 = 8 KB

  ds_main<<<GX, TB, 0, stream>>>(Pr, Ps, T, E, part);
  ds_finalize<<<1, 256, 0, stream>>>(part, out);
}